// Round 9
// baseline (77.490 us; speedup 1.0000x reference)
//
#include <hip/hip_runtime.h>
#include <hip/hip_bf16.h>
#include <stdint.h>

// HashedLinear: C[1024][4096] = x[1024][4096] @ w[indx[4096][4096]] + b
#define M_DIM 1024
#define K_DIM 4096
#define N_DIM 4096
#define NW    65536

typedef __bf16 bf16x8 __attribute__((ext_vector_type(8)));
typedef float  f32x4  __attribute__((ext_vector_type(4)));

// float -> bf16 round-to-nearest-even (bit trick; inputs are normal floats)
__device__ __forceinline__ unsigned short f2bf(float f) {
  unsigned u = __float_as_uint(f);
  u += 0x7fffu + ((u >> 16) & 1u);
  return (unsigned short)(u >> 16);
}

__device__ __forceinline__ void load_lds16(const void* g, void* l) {
  __builtin_amdgcn_global_load_lds((const __attribute__((address_space(1))) void*)g,
                                   (__attribute__((address_space(3))) void*)l,
                                   16, 0, 0);
}

// ---- kernel 1: convert x and w to bf16 (stored as ushort) ----
__global__ void prep_kernel(const float* __restrict__ x, const float* __restrict__ w,
                            unsigned short* __restrict__ xb, unsigned short* __restrict__ wb) {
  const int XQ = M_DIM * K_DIM / 4;
  const int WQ = NW / 4;
  int i = blockIdx.x * blockDim.x + threadIdx.x;
  if (i < XQ) {
    float4 v = reinterpret_cast<const float4*>(x)[i];
    ushort4 o;
    o.x = f2bf(v.x); o.y = f2bf(v.y); o.z = f2bf(v.z); o.w = f2bf(v.w);
    reinterpret_cast<ushort4*>(xb)[i] = o;
  } else if (i < XQ + WQ) {
    int j = i - XQ;
    float4 v = reinterpret_cast<const float4*>(w)[j];
    ushort4 o;
    o.x = f2bf(v.x); o.y = f2bf(v.y); o.z = f2bf(v.z); o.w = f2bf(v.w);
    reinterpret_cast<ushort4*>(wb)[j] = o;
  }
}

// ---- kernel 2: gather + transpose with the WHOLE pool staged in LDS ----
// (at its ~15 us streaming roofline: 64 MB indx + 32 MB Bt + pool staging)
__global__ __launch_bounds__(1024)
void gather_kernel(const int* __restrict__ indx,
                   const unsigned short* __restrict__ wb,
                   unsigned short* __restrict__ Bt) {
  __shared__ unsigned short pool[NW];        // 128 KB
  __shared__ unsigned short tile[64][68];    // 8.5 KB
  int t = threadIdx.x;

  {
    const uint4* src = reinterpret_cast<const uint4*>(wb);
    uint4* dst = reinterpret_cast<uint4*>(pool);
#pragma unroll
    for (int i = 0; i < 8; ++i) dst[t + i * 1024] = src[t + i * 1024];
  }

  int r  = t >> 4, cq = t & 15;   // load-phase coords (k-row, n-quad)
  int nn = t >> 4, kq = t & 15;   // write-phase coords (n-row, k-quad)
  int base_tid = blockIdx.x * 16;

  int4 id;
  {
    int k0 = ((base_tid >> 6) << 6), n0 = ((base_tid & 63) << 6);
    id = *reinterpret_cast<const int4*>(indx + (size_t)(k0 + r) * N_DIM + n0 + cq * 4);
  }
  __syncthreads();  // pool ready

  for (int it = 0; it < 16; ++it) {
    int tid = base_tid + it;
    int k0 = ((tid >> 6) << 6), n0 = ((tid & 63) << 6);

    int4 idn = id;
    if (it < 15) {
      int tid2 = tid + 1;
      int k02 = ((tid2 >> 6) << 6), n02 = ((tid2 & 63) << 6);
      idn = *reinterpret_cast<const int4*>(indx + (size_t)(k02 + r) * N_DIM + n02 + cq * 4);
    }

    tile[r][cq * 4 + 0] = pool[id.x];
    tile[r][cq * 4 + 1] = pool[id.y];
    tile[r][cq * 4 + 2] = pool[id.z];
    tile[r][cq * 4 + 3] = pool[id.w];
    __syncthreads();

    ushort4 o;
    o.x = tile[kq * 4 + 0][nn];
    o.y = tile[kq * 4 + 1][nn];
    o.z = tile[kq * 4 + 2][nn];
    o.w = tile[kq * 4 + 3][nn];
    *reinterpret_cast<ushort4*>(Bt + (size_t)(n0 + nn) * K_DIM + k0 + kq * 4) = o;
    __syncthreads();

    id = idn;
  }
}

// ---- kernel 3: bf16 MFMA GEMM, 4-wave 64x64 wave tiles, fine-phase dbuf ----
// LDS-traffic-optimized: 2x2 wave grid halves A/B frag duplication
// (96->64 KB LDS reads per 128^2 x 64 chunk), 32 MFMA per barrier, and
// 64 KB dbuf => 2 blocks/CU (cross-block overlap covers boundary drain).
#define BM 128
#define BN 128
#define BK 64

__global__ __launch_bounds__(256, 2)
void gemm_kernel(const unsigned short* __restrict__ A,   // x bf16 [M][K]
                 const unsigned short* __restrict__ Bt,  // B^T bf16 [N][K]
                 const float* __restrict__ bias,
                 float* __restrict__ C) {                // [M][N] f32
  __shared__ unsigned short As[2][BM * BK];  // 2 x 16 KB
  __shared__ unsigned short Bs[2][BN * BK];  // 2 x 16 KB

  int t = threadIdx.x;                // 0..255
  int lane = t & 63, wid = t >> 6;    // 4 waves
  int wm = wid >> 1, wn = wid & 1;    // 2x2 wave grid; wave tile 64x64

  // XCD swizzle: grid 256 (%8==0). XCD x gets by in [x*4, x*4+4): 4 N-panels
  // = 4 MB Bt (L2-resident) and all 8 M-tiles (A = 8 MB, L3-resident).
  int bid = blockIdx.x;
  int swz = (bid & 7) * 32 + (bid >> 3);
  int bx = swz & 7, by = swz >> 3;    // bx: M-tile (8), by: N-tile (32)
  int m0 = bx * BM, n0 = by * BN;

  const unsigned short* Ag = A  + (size_t)m0 * K_DIM;
  const unsigned short* Bg = Bt + (size_t)n0 * K_DIM;

  f32x4 acc[4][4];
#pragma unroll
  for (int i = 0; i < 4; ++i)
#pragma unroll
    for (int j = 0; j < 4; ++j)
      acc[i][j] = (f32x4){0.f, 0.f, 0.f, 0.f};

  int fr = lane & 15, hc = lane >> 4;  // frag row, k-half-chunk

  // Staging: A tile 128 rows x 8 chunks = 1024 chunks, B same; 256 threads
  // -> 4 A-chunks + 4 B-chunks per thread per K-step, all issued in phase A.
  // LDS linear dest; swizzle via GLOBAL source chunk permute s^(r&7).
#define STAGE_A(dst, kb)                                                      \
  do {                                                                        \
    _Pragma("unroll")                                                         \
    for (int i_ = 0; i_ < 4; ++i_) {                                          \
      int c_ = t + i_ * 256;                                                  \
      int r_ = c_ >> 3, s_ = c_ & 7;                                          \
      load_lds16(Ag + (size_t)r_ * K_DIM + (kb) + ((s_ ^ (r_ & 7)) << 3),     \
                 (char*)(dst) + c_ * 16);                                     \
    }                                                                         \
  } while (0)
#define STAGE_B(dst, kb)                                                      \
  do {                                                                        \
    _Pragma("unroll")                                                         \
    for (int i_ = 0; i_ < 4; ++i_) {                                          \
      int c_ = t + i_ * 256;                                                  \
      int r_ = c_ >> 3, s_ = c_ & 7;                                          \
      load_lds16(Bg + (size_t)r_ * K_DIM + (kb) + ((s_ ^ (r_ & 7)) << 3),     \
                 (char*)(dst) + c_ * 16);                                     \
    }                                                                         \
  } while (0)

  unsigned short *a0 = As[0], *a1 = As[1];
  unsigned short *b0 = Bs[0], *b1 = Bs[1];

  STAGE_A(a0, 0);
  STAGE_B(b0, 0);
  asm volatile("s_waitcnt vmcnt(0)" ::: "memory");
  __builtin_amdgcn_sched_barrier(0);
  __builtin_amdgcn_s_barrier();
  __builtin_amdgcn_sched_barrier(0);

  const int NT = K_DIM / BK;  // 64
  for (int kt = 0; kt < NT; ++kt) {
    const bool pf = (kt + 1 < NT);
    const int kb1 = (kt + 1) * BK;

    // ---- phase A (kk=0): ds_read half0 | stage ALL of next tile | MFMA ----
    {
      bf16x8 af[4], bfv[4];
#pragma unroll
      for (int mi = 0; mi < 4; ++mi) {
        int row = wm * 64 + mi * 16 + fr;
        int q = hc ^ (row & 7);
        af[mi] = *reinterpret_cast<const bf16x8*>((char*)a0 + row * 128 + q * 16);
      }
#pragma unroll
      for (int ni = 0; ni < 4; ++ni) {
        int row = wn * 64 + ni * 16 + fr;
        int q = hc ^ (row & 7);
        bfv[ni] = *reinterpret_cast<const bf16x8*>((char*)b0 + row * 128 + q * 16);
      }
      if (pf) { STAGE_A(a1, kb1); STAGE_B(b1, kb1); }  // 8 loads, ~2 phases early
      __builtin_amdgcn_s_setprio(1);
#pragma unroll
      for (int mi = 0; mi < 4; ++mi)
#pragma unroll
        for (int ni = 0; ni < 4; ++ni)
          acc[mi][ni] = __builtin_amdgcn_mfma_f32_16x16x32_bf16(af[mi], bfv[ni], acc[mi][ni], 0, 0, 0);
      __builtin_amdgcn_s_setprio(0);
    }

    // ---- phase B (kk=1): ds_read half1 | MFMA ----
    {
      bf16x8 af[4], bfv[4];
#pragma unroll
      for (int mi = 0; mi < 4; ++mi) {
        int row = wm * 64 + mi * 16 + fr;
        int q = (hc + 4) ^ (row & 7);
        af[mi] = *reinterpret_cast<const bf16x8*>((char*)a0 + row * 128 + q * 16);
      }
#pragma unroll
      for (int ni = 0; ni < 4; ++ni) {
        int row = wn * 64 + ni * 16 + fr;
        int q = (hc + 4) ^ (row & 7);
        bfv[ni] = *reinterpret_cast<const bf16x8*>((char*)b0 + row * 128 + q * 16);
      }
      __builtin_amdgcn_s_setprio(1);
#pragma unroll
      for (int mi = 0; mi < 4; ++mi)
#pragma unroll
        for (int ni = 0; ni < 4; ++ni)
          acc[mi][ni] = __builtin_amdgcn_mfma_f32_16x16x32_bf16(af[mi], bfv[ni], acc[mi][ni], 0, 0, 0);
      __builtin_amdgcn_s_setprio(0);
    }

    // ---- boundary: next tile ready + all waves done reading cur ----
    asm volatile("s_waitcnt vmcnt(0)" ::: "memory");  // loads issued ~2 phases ago
    __builtin_amdgcn_sched_barrier(0);
    __builtin_amdgcn_s_barrier();
    __builtin_amdgcn_sched_barrier(0);

    unsigned short* ta = a0; a0 = a1; a1 = ta;
    unsigned short* tb = b0; b0 = b1; b1 = tb;
  }

  // epilogue: C/D layout col = lane&15, row = (lane>>4)*4 + j  (m89-verified)
  int fq = lane >> 4;
#pragma unroll
  for (int ni = 0; ni < 4; ++ni) {
    int gc = n0 + wn * 64 + ni * 16 + fr;
    float bv = bias[gc];
#pragma unroll
    for (int mi = 0; mi < 4; ++mi) {
      int gr = m0 + wm * 64 + mi * 16 + fq * 4;
#pragma unroll
      for (int j = 0; j < 4; ++j)
        C[(size_t)(gr + j) * N_DIM + gc] = acc[mi][ni][j] + bv;
    }
  }
#undef STAGE_A
#undef STAGE_B
}

extern "C" void kernel_launch(void* const* d_in, const int* in_sizes, int n_in,
                              void* d_out, int out_size, void* d_ws, size_t ws_size,
                              hipStream_t stream) {
  const float* x    = (const float*)d_in[0];
  const float* w    = (const float*)d_in[1];
  const float* b    = (const float*)d_in[2];
  const int*   indx = (const int*)d_in[3];
  float* out = (float*)d_out;

  // workspace: xb (8 MB) | wb (128 KB) | Bt (32 MB)
  unsigned short* xb = (unsigned short*)d_ws;
  unsigned short* wb = xb + (size_t)M_DIM * K_DIM;
  unsigned short* Bt = wb + NW;

  int prep_total = (M_DIM * K_DIM + NW) / 4;
  prep_kernel<<<(prep_total + 255) / 256, 256, 0, stream>>>(x, w, xb, wb);
  gather_kernel<<<256, 1024, 0, stream>>>(indx, wb, Bt);
  gemm_kernel<<<256, 256, 0, stream>>>(xb, Bt, b, out);
}

// Round 10
// 61.673 us; speedup vs baseline: 1.2565x; 1.2565x over previous
//
#include <hip/hip_runtime.h>
#include <hip/hip_bf16.h>
#include <stdint.h>

// HashedLinear: C[1024][4096] = x[1024][4096] @ w[indx[4096][4096]] + b
#define M_DIM 1024
#define K_DIM 4096
#define N_DIM 4096
#define NW    65536

typedef __bf16 bf16x8 __attribute__((ext_vector_type(8)));
typedef float  f32x4  __attribute__((ext_vector_type(4)));

// float -> bf16 round-to-nearest-even (bit trick; inputs are normal floats)
__device__ __forceinline__ unsigned short f2bf(float f) {
  unsigned u = __float_as_uint(f);
  u += 0x7fffu + ((u >> 16) & 1u);
  return (unsigned short)(u >> 16);
}

__device__ __forceinline__ void load_lds16(const void* g, void* l) {
  __builtin_amdgcn_global_load_lds((const __attribute__((address_space(1))) void*)g,
                                   (__attribute__((address_space(3))) void*)l,
                                   16, 0, 0);
}

// ---- kernel 1: convert x and w to bf16 (stored as ushort) ----
__global__ void prep_kernel(const float* __restrict__ x, const float* __restrict__ w,
                            unsigned short* __restrict__ xb, unsigned short* __restrict__ wb) {
  const int XQ = M_DIM * K_DIM / 4;
  const int WQ = NW / 4;
  int i = blockIdx.x * blockDim.x + threadIdx.x;
  if (i < XQ) {
    float4 v = reinterpret_cast<const float4*>(x)[i];
    ushort4 o;
    o.x = f2bf(v.x); o.y = f2bf(v.y); o.z = f2bf(v.z); o.w = f2bf(v.w);
    reinterpret_cast<ushort4*>(xb)[i] = o;
  } else if (i < XQ + WQ) {
    int j = i - XQ;
    float4 v = reinterpret_cast<const float4*>(w)[j];
    ushort4 o;
    o.x = f2bf(v.x); o.y = f2bf(v.y); o.z = f2bf(v.z); o.w = f2bf(v.w);
    reinterpret_cast<ushort4*>(wb)[j] = o;
  }
}

// ---- kernel 2: gather + transpose with the WHOLE pool staged in LDS ----
// (at its ~15 us streaming roofline: 64 MB indx + 32 MB Bt + pool staging)
__global__ __launch_bounds__(1024)
void gather_kernel(const int* __restrict__ indx,
                   const unsigned short* __restrict__ wb,
                   unsigned short* __restrict__ Bt) {
  __shared__ unsigned short pool[NW];        // 128 KB
  __shared__ unsigned short tile[64][68];    // 8.5 KB
  int t = threadIdx.x;

  {
    const uint4* src = reinterpret_cast<const uint4*>(wb);
    uint4* dst = reinterpret_cast<uint4*>(pool);
#pragma unroll
    for (int i = 0; i < 8; ++i) dst[t + i * 1024] = src[t + i * 1024];
  }

  int r  = t >> 4, cq = t & 15;   // load-phase coords (k-row, n-quad)
  int nn = t >> 4, kq = t & 15;   // write-phase coords (n-row, k-quad)
  int base_tid = blockIdx.x * 16;

  int4 id;
  {
    int k0 = ((base_tid >> 6) << 6), n0 = ((base_tid & 63) << 6);
    id = *reinterpret_cast<const int4*>(indx + (size_t)(k0 + r) * N_DIM + n0 + cq * 4);
  }
  __syncthreads();  // pool ready

  for (int it = 0; it < 16; ++it) {
    int tid = base_tid + it;
    int k0 = ((tid >> 6) << 6), n0 = ((tid & 63) << 6);

    int4 idn = id;
    if (it < 15) {
      int tid2 = tid + 1;
      int k02 = ((tid2 >> 6) << 6), n02 = ((tid2 & 63) << 6);
      idn = *reinterpret_cast<const int4*>(indx + (size_t)(k02 + r) * N_DIM + n02 + cq * 4);
    }

    tile[r][cq * 4 + 0] = pool[id.x];
    tile[r][cq * 4 + 1] = pool[id.y];
    tile[r][cq * 4 + 2] = pool[id.z];
    tile[r][cq * 4 + 3] = pool[id.w];
    __syncthreads();

    ushort4 o;
    o.x = tile[kq * 4 + 0][nn];
    o.y = tile[kq * 4 + 1][nn];
    o.z = tile[kq * 4 + 2][nn];
    o.w = tile[kq * 4 + 3][nn];
    *reinterpret_cast<ushort4*>(Bt + (size_t)(n0 + nn) * K_DIM + k0 + kq * 4) = o;
    __syncthreads();

    id = idn;
  }
}

// ---- kernel 3: bf16 MFMA GEMM, 8-wave kk-split (2M x 2N x 2K wave grid) ----
// R8's proven fine-phase skeleton (3-buffer, counted vmcnt(4), setprio) with
// 64x64 wave tiles: kg=0 waves process k-chunks 0-3, kg=1 chunks 4-7 of each
// BK=64 tile. LDS frag reads drop 96->64 KB/K-step at unchanged 8 waves/CU.
// Partial accumulators combined via LDS reduction in the epilogue.
#define BM 128
#define BN 128
#define BK 64

__global__ __launch_bounds__(512)
void gemm_kernel(const unsigned short* __restrict__ A,   // x bf16 [M][K]
                 const unsigned short* __restrict__ Bt,  // B^T bf16 [N][K]
                 const float* __restrict__ bias,
                 float* __restrict__ C) {                // [M][N] f32
  // one 96 KB arena: 3xA-tile (48 KB) + 3xB-tile (48 KB); reused as the
  // 64 KB f32x4 reduction buffer in the epilogue.
  __shared__ __align__(16) char smem[(3 * BM * BK + 3 * BN * BK) * 2];
  unsigned short* Asb = (unsigned short*)smem;
  unsigned short* Bsb = Asb + 3 * BM * BK;

  int t = threadIdx.x;                 // 0..511
  int lane = t & 63, wid = t >> 6;     // 8 waves
  int kg = wid >> 2;                   // k-group (0: chunks 0-3, 1: chunks 4-7)
  int wm = (wid >> 1) & 1, wn = wid & 1;  // 2x2 spatial grid; wave tile 64x64

  // XCD swizzle: grid 256 (%8==0). XCD x gets by in [x*4, x*4+4): 4 N-panels
  // = 4 MB Bt (L2-resident) and all 8 M-tiles (A = 8 MB, L3-resident).
  int bid = blockIdx.x;
  int swz = (bid & 7) * 32 + (bid >> 3);
  int bx = swz & 7, by = swz >> 3;     // bx: M-tile (8), by: N-tile (32)
  int m0 = bx * BM, n0 = by * BN;

  const unsigned short* Ag = A  + (size_t)m0 * K_DIM;
  const unsigned short* Bg = Bt + (size_t)n0 * K_DIM;

  f32x4 acc[4][4];
#pragma unroll
  for (int i = 0; i < 4; ++i)
#pragma unroll
    for (int j = 0; j < 4; ++j)
      acc[i][j] = (f32x4){0.f, 0.f, 0.f, 0.f};

  int fr = lane & 15, hc = lane >> 4;  // frag row, k-quarter-chunk
  int hq = hc + 4 * kg;                // this wave's logical k-chunk (0-7)

  // Staging: A tile 128 rows x 8 chunks = 1024 chunks; 512 threads -> 2 each.
  // LDS linear dest; swizzle via GLOBAL source chunk permute s^(r&7).
#define STAGE_A(dst, kb)                                                      \
  do {                                                                        \
    _Pragma("unroll")                                                         \
    for (int i_ = 0; i_ < 2; ++i_) {                                          \
      int c_ = t + i_ * 512;                                                  \
      int r_ = c_ >> 3, s_ = c_ & 7;                                          \
      load_lds16(Ag + (size_t)r_ * K_DIM + (kb) + ((s_ ^ (r_ & 7)) << 3),     \
                 (char*)(dst) + c_ * 16);                                     \
    }                                                                         \
  } while (0)
#define STAGE_B(dst, kb)                                                      \
  do {                                                                        \
    _Pragma("unroll")                                                         \
    for (int i_ = 0; i_ < 2; ++i_) {                                          \
      int c_ = t + i_ * 512;                                                  \
      int r_ = c_ >> 3, s_ = c_ & 7;                                          \
      load_lds16(Bg + (size_t)r_ * K_DIM + (kb) + ((s_ ^ (r_ & 7)) << 3),     \
                 (char*)(dst) + c_ * 16);                                     \
    }                                                                         \
  } while (0)

  unsigned short *a0 = Asb, *a1 = Asb + BM * BK, *a2 = Asb + 2 * BM * BK;
  unsigned short *b0 = Bsb, *b1 = Bsb + BN * BK, *b2 = Bsb + 2 * BN * BK;

  STAGE_A(a0, 0);  STAGE_B(b0, 0);    // 4 in flight (tile 0)
  STAGE_A(a1, BK); STAGE_B(b1, BK);   // 8 in flight (tiles 0,1)
  asm volatile("s_waitcnt vmcnt(4)" ::: "memory");  // tile 0 ready
  __builtin_amdgcn_sched_barrier(0);
  __builtin_amdgcn_s_barrier();
  __builtin_amdgcn_sched_barrier(0);

  const int NT = K_DIM / BK;  // 64
  for (int kt = 0; kt < NT; ++kt) {
    const bool pf = (kt + 2 < NT);
    const int kb2 = (kt + 2) * BK;

    bf16x8 af[4], bfv[4];
    // ---- phase A: read A frags + half of B | stage next A | 8 MFMA ----
#pragma unroll
    for (int mi = 0; mi < 4; ++mi) {
      int row = wm * 64 + mi * 16 + fr;
      int q = hq ^ (row & 7);
      af[mi] = *reinterpret_cast<const bf16x8*>((char*)a0 + row * 128 + q * 16);
    }
#pragma unroll
    for (int ni = 0; ni < 2; ++ni) {
      int row = wn * 64 + ni * 16 + fr;
      int q = hq ^ (row & 7);
      bfv[ni] = *reinterpret_cast<const bf16x8*>((char*)b0 + row * 128 + q * 16);
    }
    if (pf) STAGE_A(a2, kb2);
    __builtin_amdgcn_s_setprio(1);
#pragma unroll
    for (int mi = 0; mi < 4; ++mi)
#pragma unroll
      for (int ni = 0; ni < 2; ++ni)
        acc[mi][ni] = __builtin_amdgcn_mfma_f32_16x16x32_bf16(af[mi], bfv[ni], acc[mi][ni], 0, 0, 0);
    __builtin_amdgcn_s_setprio(0);

    // ---- phase B: read other half of B | stage next B | 8 MFMA ----
#pragma unroll
    for (int ni = 2; ni < 4; ++ni) {
      int row = wn * 64 + ni * 16 + fr;
      int q = hq ^ (row & 7);
      bfv[ni] = *reinterpret_cast<const bf16x8*>((char*)b0 + row * 128 + q * 16);
    }
    if (pf) STAGE_B(b2, kb2);
    __builtin_amdgcn_s_setprio(1);
#pragma unroll
    for (int mi = 0; mi < 4; ++mi)
#pragma unroll
      for (int ni = 2; ni < 4; ++ni)
        acc[mi][ni] = __builtin_amdgcn_mfma_f32_16x16x32_bf16(af[mi], bfv[ni], acc[mi][ni], 0, 0, 0);
    __builtin_amdgcn_s_setprio(0);

    // ---- boundary: tile kt+1 ready (counted, never 0 mid-loop) ----
    if (pf) {
      asm volatile("s_waitcnt vmcnt(4)" ::: "memory");  // kt+2's 4 stay in flight
    } else {
      asm volatile("s_waitcnt vmcnt(0)" ::: "memory");  // tail: drain
    }
    __builtin_amdgcn_sched_barrier(0);
    __builtin_amdgcn_s_barrier();
    __builtin_amdgcn_sched_barrier(0);

    unsigned short* ta = a0; a0 = a1; a1 = a2; a2 = ta;
    unsigned short* tb = b0; b0 = b1; b1 = b2; b2 = tb;
  }

  // ---- epilogue: combine kg=0 / kg=1 partials, add bias, store C ----
  // kg=1 waves write acc to LDS (contiguous b128 pattern, conflict-free);
  // kg=0 waves add and write out. red = 4 pairs x 64 lanes x 16 f32x4 = 64 KB.
  f32x4* red = (f32x4*)smem;
  int p = wid & 3;  // pair id (wm*2+wn)
  if (kg == 1) {
#pragma unroll
    for (int mi = 0; mi < 4; ++mi)
#pragma unroll
      for (int ni = 0; ni < 4; ++ni)
        red[((mi * 4 + ni) * 4 + p) * 64 + lane] = acc[mi][ni];
  }
  __syncthreads();
  if (kg == 0) {
    int fq = lane >> 4;
#pragma unroll
    for (int ni = 0; ni < 4; ++ni) {
      int gc = n0 + wn * 64 + ni * 16 + fr;
      float bv = bias[gc];
#pragma unroll
      for (int mi = 0; mi < 4; ++mi) {
        f32x4 v = acc[mi][ni] + red[((mi * 4 + ni) * 4 + p) * 64 + lane];
        int gr = m0 + wm * 64 + mi * 16 + fq * 4;
#pragma unroll
        for (int j = 0; j < 4; ++j)
          C[(size_t)(gr + j) * N_DIM + gc] = v[j] + bv;
      }
    }
  }
#undef STAGE_A
#undef STAGE_B
}

extern "C" void kernel_launch(void* const* d_in, const int* in_sizes, int n_in,
                              void* d_out, int out_size, void* d_ws, size_t ws_size,
                              hipStream_t stream) {
  const float* x    = (const float*)d_in[0];
  const float* w    = (const float*)d_in[1];
  const float* b    = (const float*)d_in[2];
  const int*   indx = (const int*)d_in[3];
  float* out = (float*)d_out;

  // workspace: xb (8 MB) | wb (128 KB) | Bt (32 MB)
  unsigned short* xb = (unsigned short*)d_ws;
  unsigned short* wb = xb + (size_t)M_DIM * K_DIM;
  unsigned short* Bt = wb + NW;

  int prep_total = (M_DIM * K_DIM + NW) / 4;
  prep_kernel<<<(prep_total + 255) / 256, 256, 0, stream>>>(x, w, xb, wb);
  gather_kernel<<<256, 1024, 0, stream>>>(indx, wb, Bt);
  gemm_kernel<<<256, 512, 0, stream>>>(xb, Bt, b, out);
}